// Round 1
// baseline (934.852 us; speedup 1.0000x reference)
//
#include <hip/hip_runtime.h>

typedef unsigned short u16;
typedef float f32x4 __attribute__((ext_vector_type(4)));
typedef __bf16 bf16x8 __attribute__((ext_vector_type(8)));
typedef unsigned short u16x8 __attribute__((ext_vector_type(8)));

#define C_DIM 640
#define HW_DIM 441
#define QN 75
#define SN 25
#define WAYS 5
#define MROWS 33075   // 75*441
#define MPAD  33152   // 259*128
#define MBLK  259
#define NWAY  2205    // 5*441
#define NPAD  2304    // 18*128
#define NTILES 18

__device__ __forceinline__ u16 f2bf(float f) {
  unsigned u = __builtin_bit_cast(unsigned, f);
  u += 0x7FFFu + ((u >> 16) & 1u);   // round-to-nearest-even
  return (u16)(u >> 16);
}

__device__ __forceinline__ void glds16(const void* g, void* l) {
  __builtin_amdgcn_global_load_lds(
      (__attribute__((address_space(1))) unsigned int*)g,
      (__attribute__((address_space(3))) unsigned int*)l, 16, 0, 0);
}

// ---------------------------------------------------------------------------
// Zero the pad rows of A / B and the output accumulator (ws/out are poisoned
// with 0xAA before every timed launch).
// ---------------------------------------------------------------------------
__global__ void zero_pad(u16* __restrict__ Abf, u16* __restrict__ Sbf,
                         float* __restrict__ out) {
  int i = blockIdx.x * 256 + threadIdx.x;
  if (i < 49280) {                                  // (MPAD-MROWS)*640
    Abf[(size_t)MROWS * C_DIM + i] = 0;
    return;
  }
  i -= 49280;
  if (i < 316800) {                                 // 5*(NPAD-NWAY)*640
    const int w = i / 63360;
    const int r = i % 63360;
    Sbf[((size_t)w * NPAD + NWAY) * C_DIM + r] = 0;
    return;
  }
  i -= 316800;
  if (i < QN * WAYS) out[i] = 0.f;
}

// ---------------------------------------------------------------------------
// Normalize each (img, hw) descriptor over C and emit bf16, transposed to
// [row][c] with c contiguous (MFMA-fragment-friendly). Queries: row=q*441+m.
// Support: row = way*2304 + shot*441 + m.
// Grid: nimg*7 blocks (7 m-tiles of 64), 256 threads.
// ---------------------------------------------------------------------------
__global__ __launch_bounds__(256)
void prep_norm_transpose(const float* __restrict__ src, u16* __restrict__ dst,
                         int support) {
  const int bid = blockIdx.x;
  const int img = bid / 7;
  const int mt = bid % 7;
  const int m0 = mt * 64;
  const int t = threadIdx.x;
  const int mloc = t & 63;
  const int cpart = t >> 6;                 // 0..3
  const int m = m0 + mloc;
  const int m_eff = (m < HW_DIM) ? m : (HW_DIM - 1);
  const float* base = src + (size_t)img * (C_DIM * HW_DIM);

  // ---- phase 1: sum of squares over C (4-way c-split) ----
  float ss = 0.f;
  const int c0 = cpart * 160;
  for (int c = c0; c < c0 + 160; ++c) {
    float v = base[(size_t)c * HW_DIM + m_eff];
    ss += v * v;
  }
  __shared__ float red[256];
  __shared__ float inv[64];
  red[t] = ss;
  __syncthreads();
  if (t < 64) {
    float s4 = red[t] + red[t + 64] + red[t + 128] + red[t + 192];
    inv[t] = rsqrtf(s4);
  }
  __syncthreads();

  size_t drow0;
  if (support) {
    const int w = img / 5, shot = img % 5;
    drow0 = (size_t)w * NPAD + (size_t)shot * HW_DIM;
  } else {
    drow0 = (size_t)img * HW_DIM;
  }

  // ---- phase 2: tiled transpose through LDS, normalize + cvt to bf16 ----
  __shared__ u16 T[64][72];                 // +8 pad, rows 16B aligned
  const float iv = inv[mloc];
  const int mw = t >> 2;
  const int cg = t & 3;
  const int m_out = m0 + mw;

  for (int ct = 0; ct < 10; ++ct) {
    u16 tmp[16];
#pragma unroll
    for (int ci = 0; ci < 16; ++ci) {
      const int c = ct * 64 + cpart * 16 + ci;
      tmp[ci] = f2bf(base[(size_t)c * HW_DIM + m_eff] * iv);
    }
    __syncthreads();                        // previous tile fully consumed
    u16x8 w0 = {tmp[0], tmp[1], tmp[2], tmp[3], tmp[4], tmp[5], tmp[6], tmp[7]};
    u16x8 w1 = {tmp[8], tmp[9], tmp[10], tmp[11], tmp[12], tmp[13], tmp[14], tmp[15]};
    *(u16x8*)&T[mloc][cpart * 16] = w0;
    *(u16x8*)&T[mloc][cpart * 16 + 8] = w1;
    __syncthreads();
    if (m_out < HW_DIM) {
      const u16x8 v0 = *(const u16x8*)&T[mw][cg * 16];
      const u16x8 v1 = *(const u16x8*)&T[mw][cg * 16 + 8];
      u16* drow = dst + (drow0 + m_out) * C_DIM + ct * 64 + cg * 16;
      *(u16x8*)drow = v0;
      *(u16x8*)(drow + 8) = v1;
    }
  }
}

// ---------------------------------------------------------------------------
// Fused cosine-sim GEMM + per-row top-3 + sum.
// Grid: 5 ways * 259 m-chunks. Block: 256 threads (4 waves, 2x2 of 64x64).
// ---------------------------------------------------------------------------
__global__ __launch_bounds__(256, 2)
void simtopk(const u16* __restrict__ Abf, const u16* __restrict__ Sbf,
             float* __restrict__ out) {
  __shared__ u16 As[128 * 64];              // XOR-swizzled [m][kq^ (m&7)]
  __shared__ u16 Bs[128 * 64];
  __shared__ float part[2][128][4];
  __shared__ float qsum[2];

  const int bid = blockIdx.x;
  const int way = bid / MBLK;               // way-major: L2 locality on Sbf
  const int mc = bid % MBLK;
  const int R0 = mc * 128;
  const int tid = threadIdx.x;
  const int lane = tid & 63;
  const int wv = tid >> 6;
  const int wm = (wv >> 1) * 64;
  const int wn = (wv & 1) * 64;
  const int l15 = lane & 15;
  const int l4 = lane >> 4;

  if (tid < 2) qsum[tid] = 0.f;

  float t0[16], t1[16], t2[16];             // per-lane top-3, 16 row slots
#pragma unroll
  for (int r = 0; r < 16; ++r) { t0[r] = -1e30f; t1[r] = -1e30f; t2[r] = -1e30f; }

  const u16* Sway = Sbf + (size_t)way * NPAD * C_DIM;
  const int srow = lane >> 3;               // staging: row within 8-row strip
  const int kqp_st = lane & 7;              // staging: physical k-quad

  for (int nt = 0; nt < NTILES; ++nt) {
    f32x4 acc[4][4];
    const f32x4 z4 = {0.f, 0.f, 0.f, 0.f};
#pragma unroll
    for (int mi = 0; mi < 4; ++mi)
#pragma unroll
      for (int ni = 0; ni < 4; ++ni) acc[mi][ni] = z4;

    for (int kt = 0; kt < 10; ++kt) {
      __syncthreads();                      // previous iter's ds_reads done
      // stage A tile (rows R0..R0+127, k = kt*64..+63), swizzled source addr
#pragma unroll
      for (int j = 0; j < 4; ++j) {
        const int i = wv * 4 + j;
        const int mrow = i * 8 + srow;
        const int kql = kqp_st ^ (mrow & 7);
        glds16(Abf + (size_t)(R0 + mrow) * C_DIM + kt * 64 + kql * 8,
               As + i * 512);
      }
#pragma unroll
      for (int j = 0; j < 4; ++j) {
        const int i = wv * 4 + j;
        const int nrow = i * 8 + srow;
        const int kql = kqp_st ^ (nrow & 7);
        glds16(Sway + (size_t)(nt * 128 + nrow) * C_DIM + kt * 64 + kql * 8,
               Bs + i * 512);
      }
      __syncthreads();                      // drains vmcnt -> LDS visible
#pragma unroll
      for (int s = 0; s < 2; ++s) {
        bf16x8 af[4], bfr[4];
#pragma unroll
        for (int mi = 0; mi < 4; ++mi) {
          const int row = wm + mi * 16 + l15;
          const int kqp = (s * 4 + l4) ^ (row & 7);
          af[mi] = __builtin_bit_cast(bf16x8, *(const u16x8*)(As + row * 64 + kqp * 8));
        }
#pragma unroll
        for (int ni = 0; ni < 4; ++ni) {
          const int row = wn + ni * 16 + l15;
          const int kqp = (s * 4 + l4) ^ (row & 7);
          bfr[ni] = __builtin_bit_cast(bf16x8, *(const u16x8*)(Bs + row * 64 + kqp * 8));
        }
#pragma unroll
        for (int mi = 0; mi < 4; ++mi)
#pragma unroll
          for (int ni = 0; ni < 4; ++ni)
            acc[mi][ni] = __builtin_amdgcn_mfma_f32_16x16x32_bf16(
                af[mi], bfr[ni], acc[mi][ni], 0, 0, 0);
      }
    }

    // branchless top-3 insert (t0>=t1>=t2), VALU pipe overlaps MFMA waves
    const bool lastTile = (nt == NTILES - 1);
#pragma unroll
    for (int ni = 0; ni < 4; ++ni) {
      const int ncol = nt * 128 + wn + ni * 16 + l15;
      const bool bad = lastTile && (ncol >= NWAY);
#pragma unroll
      for (int mi = 0; mi < 4; ++mi)
#pragma unroll
        for (int i = 0; i < 4; ++i) {
          float v = acc[mi][ni][i];
          if (bad) v = -1e30f;
          const int r = mi * 4 + i;
          t2[r] = fmaxf(t2[r], fminf(v, t1[r]));
          t1[r] = fmaxf(t1[r], fminf(v, t0[r]));
          t0[r] = fmaxf(t0[r], v);
        }
    }
  }

  // merge top-3 across the 16 column-lanes (same row lives in same quad)
#pragma unroll
  for (int d = 1; d <= 8; d <<= 1) {
#pragma unroll
    for (int r = 0; r < 16; ++r) {
      const float o0 = __shfl_xor(t0[r], d);
      const float o1 = __shfl_xor(t1[r], d);
      const float o2 = __shfl_xor(t2[r], d);
      t2[r] = fmaxf(t2[r], fminf(o0, t1[r]));
      t1[r] = fmaxf(t1[r], fminf(o0, t0[r]));
      t0[r] = fmaxf(t0[r], o0);
      t2[r] = fmaxf(t2[r], fminf(o1, t1[r]));
      t1[r] = fmaxf(t1[r], fminf(o1, t0[r]));
      t0[r] = fmaxf(t0[r], o1);
      t2[r] = fmaxf(t2[r], fminf(o2, t1[r]));
      t1[r] = fmaxf(t1[r], fminf(o2, t0[r]));
      t0[r] = fmaxf(t0[r], o2);
    }
  }

  // cross-wave merge (wn=0 half vs wn=64 half) through LDS
  if (l15 == 0) {
    const int p = wv & 1;
#pragma unroll
    for (int r = 0; r < 16; ++r) {
      const int mi = r >> 2, i = r & 3;
      const int row_local = wm + mi * 16 + l4 * 4 + i;
      part[p][row_local][0] = t0[r];
      part[p][row_local][1] = t1[r];
      part[p][row_local][2] = t2[r];
    }
  }
  __syncthreads();
  if (tid < 128) {
    const int grow = R0 + tid;
    if (grow < MROWS) {
      float a0 = part[0][tid][0], a1 = part[0][tid][1], a2 = part[0][tid][2];
      const float b0 = part[1][tid][0], b1 = part[1][tid][1], b2 = part[1][tid][2];
      a2 = fmaxf(a2, fminf(b0, a1)); a1 = fmaxf(a1, fminf(b0, a0)); a0 = fmaxf(a0, b0);
      a2 = fmaxf(a2, fminf(b1, a1)); a1 = fmaxf(a1, fminf(b1, a0)); a0 = fmaxf(a0, b1);
      a2 = fmaxf(a2, fminf(b2, a1)); a1 = fmaxf(a1, fminf(b2, a0)); a0 = fmaxf(a0, b2);
      const float rs = a0 + a1 + a2;
      const int qq = grow / HW_DIM;
      atomicAdd(&qsum[qq - (R0 / HW_DIM)], rs);   // block spans <= 2 q's
    }
  }
  __syncthreads();
  if (tid < 2) {
    const int qq = R0 / HW_DIM + tid;
    if (qq < QN) atomicAdd(out + qq * WAYS + way, qsum[tid]);
  }
}

// ---------------------------------------------------------------------------
extern "C" void kernel_launch(void* const* d_in, const int* in_sizes, int n_in,
                              void* d_out, int out_size, void* d_ws, size_t ws_size,
                              hipStream_t stream) {
  const float* x1 = (const float*)d_in[0];
  const float* x2 = (const float*)d_in[1];
  float* out = (float*)d_out;
  u16* Abf = (u16*)d_ws;                                        // MPAD x 640 bf16
  u16* Sbf = (u16*)((char*)d_ws + (size_t)MPAD * C_DIM * 2);    // 5 x NPAD x 640

  hipLaunchKernelGGL(zero_pad, dim3(1432), dim3(256), 0, stream, Abf, Sbf, out);
  hipLaunchKernelGGL(prep_norm_transpose, dim3(QN * 7), dim3(256), 0, stream,
                     x1, Abf, 0);
  hipLaunchKernelGGL(prep_norm_transpose, dim3(SN * 7), dim3(256), 0, stream,
                     x2, Sbf, 1);
  hipLaunchKernelGGL(simtopk, dim3(WAYS * MBLK), dim3(256), 0, stream,
                     Abf, Sbf, out);
}

// Round 2
// 886.632 us; speedup vs baseline: 1.0544x; 1.0544x over previous
//
#include <hip/hip_runtime.h>

typedef unsigned short u16;
typedef float f32x4 __attribute__((ext_vector_type(4)));
typedef __bf16 bf16x8 __attribute__((ext_vector_type(8)));
typedef unsigned short u16x8 __attribute__((ext_vector_type(8)));

#define C_DIM 640
#define HW_DIM 441
#define QN 75
#define SN 25
#define WAYS 5
#define MROWS 33075   // 75*441
#define MPAD  33152   // 259*128
#define MBLK  259
#define NWAY  2205    // 5*441
#define NPAD  2304    // 18*128
#define NTILES 18

__device__ __forceinline__ u16 f2bf(float f) {
  unsigned u = __builtin_bit_cast(unsigned, f);
  u += 0x7FFFu + ((u >> 16) & 1u);   // round-to-nearest-even
  return (u16)(u >> 16);
}

__device__ __forceinline__ void glds16(const void* g, void* l) {
  __builtin_amdgcn_global_load_lds(
      (__attribute__((address_space(1))) unsigned int*)g,
      (__attribute__((address_space(3))) unsigned int*)l, 16, 0, 0);
}

// ---------------------------------------------------------------------------
// Zero the pad rows of A / B and the output accumulator (ws/out are poisoned
// with 0xAA before every timed launch).
// ---------------------------------------------------------------------------
__global__ void zero_pad(u16* __restrict__ Abf, u16* __restrict__ Sbf,
                         float* __restrict__ out) {
  int i = blockIdx.x * 256 + threadIdx.x;
  if (i < 49280) {                                  // (MPAD-MROWS)*640
    Abf[(size_t)MROWS * C_DIM + i] = 0;
    return;
  }
  i -= 49280;
  if (i < 316800) {                                 // 5*(NPAD-NWAY)*640
    const int w = i / 63360;
    const int r = i % 63360;
    Sbf[((size_t)w * NPAD + NWAY) * C_DIM + r] = 0;
    return;
  }
  i -= 316800;
  if (i < QN * WAYS) out[i] = 0.f;
}

// ---------------------------------------------------------------------------
// Normalize each (img, hw) descriptor over C and emit bf16, transposed to
// [row][c] with c contiguous. Queries: row=q*441+m. Support: way*2304+shot*441+m.
// ---------------------------------------------------------------------------
__global__ __launch_bounds__(256)
void prep_norm_transpose(const float* __restrict__ src, u16* __restrict__ dst,
                         int support) {
  const int bid = blockIdx.x;
  const int img = bid / 7;
  const int mt = bid % 7;
  const int m0 = mt * 64;
  const int t = threadIdx.x;
  const int mloc = t & 63;
  const int cpart = t >> 6;                 // 0..3
  const int m = m0 + mloc;
  const int m_eff = (m < HW_DIM) ? m : (HW_DIM - 1);
  const float* base = src + (size_t)img * (C_DIM * HW_DIM);

  // ---- phase 1: sum of squares over C (4-way c-split) ----
  float ss = 0.f;
  const int c0 = cpart * 160;
  for (int c = c0; c < c0 + 160; ++c) {
    float v = base[(size_t)c * HW_DIM + m_eff];
    ss += v * v;
  }
  __shared__ float red[256];
  __shared__ float inv[64];
  red[t] = ss;
  __syncthreads();
  if (t < 64) {
    float s4 = red[t] + red[t + 64] + red[t + 128] + red[t + 192];
    inv[t] = rsqrtf(s4);
  }
  __syncthreads();

  size_t drow0;
  if (support) {
    const int w = img / 5, shot = img % 5;
    drow0 = (size_t)w * NPAD + (size_t)shot * HW_DIM;
  } else {
    drow0 = (size_t)img * HW_DIM;
  }

  // ---- phase 2: tiled transpose through LDS, normalize + cvt to bf16 ----
  __shared__ u16 T[64][72];                 // +8 pad, rows 16B aligned
  const float iv = inv[mloc];
  const int mw = t >> 2;
  const int cg = t & 3;
  const int m_out = m0 + mw;

  for (int ct = 0; ct < 10; ++ct) {
    u16 tmp[16];
#pragma unroll
    for (int ci = 0; ci < 16; ++ci) {
      const int c = ct * 64 + cpart * 16 + ci;
      tmp[ci] = f2bf(base[(size_t)c * HW_DIM + m_eff] * iv);
    }
    __syncthreads();                        // previous tile fully consumed
    u16x8 w0 = {tmp[0], tmp[1], tmp[2], tmp[3], tmp[4], tmp[5], tmp[6], tmp[7]};
    u16x8 w1 = {tmp[8], tmp[9], tmp[10], tmp[11], tmp[12], tmp[13], tmp[14], tmp[15]};
    *(u16x8*)&T[mloc][cpart * 16] = w0;
    *(u16x8*)&T[mloc][cpart * 16 + 8] = w1;
    __syncthreads();
    if (m_out < HW_DIM) {
      const u16x8 v0 = *(const u16x8*)&T[mw][cg * 16];
      const u16x8 v1 = *(const u16x8*)&T[mw][cg * 16 + 8];
      u16* drow = dst + (drow0 + m_out) * C_DIM + ct * 64 + cg * 16;
      *(u16x8*)drow = v0;
      *(u16x8*)(drow + 8) = v1;
    }
  }
}

// ---------------------------------------------------------------------------
// Fused cosine-sim GEMM + per-row top-3 + sum, software-pipelined:
// flat 180-iteration loop (18 nt x 10 kt), double-buffered LDS, prefetch of
// iteration t+1 issued BEFORE compute of iteration t so the barrier's
// vmcnt(0) drain waits on ~250-cycle-old loads (L2 latency hidden by ILP).
// Grid: 5 ways * 259 m-chunks. Block: 256 threads (4 waves, 2x2 of 64x64).
// ---------------------------------------------------------------------------
__global__ __launch_bounds__(256, 2)
void simtopk(const u16* __restrict__ Abf, const u16* __restrict__ Sbf,
             float* __restrict__ out) {
  // smem[0][buf] = A tile (128x64, XOR-swizzled), smem[1][buf] = B tile
  __shared__ __align__(16) u16 smem[2][2][8192];   // 64 KiB
  __shared__ float qsum[2];

  const int bid = blockIdx.x;
  const int way = bid / MBLK;               // way-major: L2 locality on Sbf
  const int mc = bid % MBLK;
  const int R0 = mc * 128;
  const int tid = threadIdx.x;
  const int lane = tid & 63;
  const int wv = tid >> 6;
  const int wm = (wv >> 1) * 64;
  const int wn = (wv & 1) * 64;
  const int l15 = lane & 15;
  const int l4 = lane >> 4;

  if (tid < 2) qsum[tid] = 0.f;

  float t0[16], t1[16], t2[16];             // per-lane top-3, 16 row slots
#pragma unroll
  for (int r = 0; r < 16; ++r) { t0[r] = -1e30f; t1[r] = -1e30f; t2[r] = -1e30f; }

  const u16* Sway = Sbf + (size_t)way * NPAD * C_DIM;
  const int srow = lane >> 3;               // staging: row within 8-row strip
  const int kqp_st = lane & 7;              // staging: physical k-quad

  // Per-thread staging source offsets (elements). Row pattern identical for
  // A and B strips; add kt*64 (+ nt*128*C_DIM for B) per iteration.
  unsigned aoff[4], boff[4];
#pragma unroll
  for (int j = 0; j < 4; ++j) {
    const int i = wv * 4 + j;
    const int row = i * 8 + srow;
    const int kql = kqp_st ^ (row & 7);
    aoff[j] = (unsigned)((R0 + row) * C_DIM + kql * 8);
    boff[j] = (unsigned)(row * C_DIM + kql * 8);
  }

  // prologue: prefetch (nt=0, kt=0) into buffer 0
#pragma unroll
  for (int j = 0; j < 4; ++j) {
    const int i = wv * 4 + j;
    glds16(Abf + aoff[j], &smem[0][0][i * 512]);
    glds16(Sway + boff[j], &smem[1][0][i * 512]);
  }

  f32x4 acc[4][4];
  const f32x4 z4 = {0.f, 0.f, 0.f, 0.f};
#pragma unroll
  for (int mi = 0; mi < 4; ++mi)
#pragma unroll
    for (int ni = 0; ni < 4; ++ni) acc[mi][ni] = z4;

  int nt = 0, kt = 0, p = 0;
  for (int t = 0; t < NTILES * 10; ++t) {
    __syncthreads();                        // buf[p] loads visible; buf[p^1] readers done

    int kt1 = kt + 1, nt1 = nt;
    if (kt1 == 10) { kt1 = 0; nt1 = nt + 1; }
    if (t < NTILES * 10 - 1) {              // prefetch t+1 into buf[p^1]
#pragma unroll
      for (int j = 0; j < 4; ++j) {
        const int i = wv * 4 + j;
        glds16(Abf + (aoff[j] + kt1 * 64), &smem[0][p ^ 1][i * 512]);
        glds16(Sway + (boff[j] + (unsigned)nt1 * (128 * C_DIM) + kt1 * 64),
               &smem[1][p ^ 1][i * 512]);
      }
    }

    const u16* Asb = smem[0][p];
    const u16* Bsb = smem[1][p];
#pragma unroll
    for (int s = 0; s < 2; ++s) {
      bf16x8 af[4], bfr[4];
#pragma unroll
      for (int mi = 0; mi < 4; ++mi) {
        const int row = wm + mi * 16 + l15;
        const int kqp = (s * 4 + l4) ^ (row & 7);
        af[mi] = __builtin_bit_cast(bf16x8, *(const u16x8*)(Asb + row * 64 + kqp * 8));
      }
#pragma unroll
      for (int ni = 0; ni < 4; ++ni) {
        const int row = wn + ni * 16 + l15;
        const int kqp = (s * 4 + l4) ^ (row & 7);
        bfr[ni] = __builtin_bit_cast(bf16x8, *(const u16x8*)(Bsb + row * 64 + kqp * 8));
      }
#pragma unroll
      for (int mi = 0; mi < 4; ++mi)
#pragma unroll
        for (int ni = 0; ni < 4; ++ni)
          acc[mi][ni] = __builtin_amdgcn_mfma_f32_16x16x32_bf16(
              af[mi], bfr[ni], acc[mi][ni], 0, 0, 0);
    }

    if (kt == 9) {
      // branchless top-3 insert (t0>=t1>=t2); VALU overlaps other waves' MFMA
      const bool lastTile = (nt == NTILES - 1);
#pragma unroll
      for (int ni = 0; ni < 4; ++ni) {
        const int ncol = nt * 128 + wn + ni * 16 + l15;
        const bool bad = lastTile && (ncol >= NWAY);
#pragma unroll
        for (int mi = 0; mi < 4; ++mi)
#pragma unroll
          for (int i = 0; i < 4; ++i) {
            float v = acc[mi][ni][i];
            if (bad) v = -1e30f;
            const int r = mi * 4 + i;
            t2[r] = fmaxf(t2[r], fminf(v, t1[r]));
            t1[r] = fmaxf(t1[r], fminf(v, t0[r]));
            t0[r] = fmaxf(t0[r], v);
            acc[mi][ni][i] = 0.f;           // re-zero for next nt
          }
      }
    }
    kt = kt1; nt = nt1; p ^= 1;
  }

  // merge top-3 across the 16 column-lanes (same row lives in same quad)
#pragma unroll
  for (int d = 1; d <= 8; d <<= 1) {
#pragma unroll
    for (int r = 0; r < 16; ++r) {
      const float o0 = __shfl_xor(t0[r], d);
      const float o1 = __shfl_xor(t1[r], d);
      const float o2 = __shfl_xor(t2[r], d);
      t2[r] = fmaxf(t2[r], fminf(o0, t1[r]));
      t1[r] = fmaxf(t1[r], fminf(o0, t0[r]));
      t0[r] = fmaxf(t0[r], o0);
      t2[r] = fmaxf(t2[r], fminf(o1, t1[r]));
      t1[r] = fmaxf(t1[r], fminf(o1, t0[r]));
      t0[r] = fmaxf(t0[r], o1);
      t2[r] = fmaxf(t2[r], fminf(o2, t1[r]));
      t1[r] = fmaxf(t1[r], fminf(o2, t0[r]));
      t0[r] = fmaxf(t0[r], o2);
    }
  }

  // cross-wave merge (wn=0 half vs wn=64 half) through LDS.
  // `part` aliases the A buffers (4 KiB < 16 KiB region): all LDS tile
  // traffic is finished (last compute read buffer p=1; region [0][0] last
  // touched two iterations back, fully drained by the loop's barriers).
  float* partf = (float*)&smem[0][0][0];    // part[p][row][c] = partf[(p*128+row)*4+c]
  if (l15 == 0) {
    const int pp = wv & 1;
#pragma unroll
    for (int r = 0; r < 16; ++r) {
      const int mi = r >> 2, i = r & 3;
      const int row_local = wm + mi * 16 + l4 * 4 + i;
      partf[((pp * 128) + row_local) * 4 + 0] = t0[r];
      partf[((pp * 128) + row_local) * 4 + 1] = t1[r];
      partf[((pp * 128) + row_local) * 4 + 2] = t2[r];
    }
  }
  __syncthreads();
  if (tid < 128) {
    const int grow = R0 + tid;
    if (grow < MROWS) {
      float a0 = partf[tid * 4 + 0], a1 = partf[tid * 4 + 1], a2 = partf[tid * 4 + 2];
      const float b0 = partf[(128 + tid) * 4 + 0];
      const float b1 = partf[(128 + tid) * 4 + 1];
      const float b2 = partf[(128 + tid) * 4 + 2];
      a2 = fmaxf(a2, fminf(b0, a1)); a1 = fmaxf(a1, fminf(b0, a0)); a0 = fmaxf(a0, b0);
      a2 = fmaxf(a2, fminf(b1, a1)); a1 = fmaxf(a1, fminf(b1, a0)); a0 = fmaxf(a0, b1);
      a2 = fmaxf(a2, fminf(b2, a1)); a1 = fmaxf(a1, fminf(b2, a0)); a0 = fmaxf(a0, b2);
      const float rs = a0 + a1 + a2;
      const int qq = grow / HW_DIM;
      atomicAdd(&qsum[qq - (R0 / HW_DIM)], rs);   // block spans <= 2 q's
    }
  }
  __syncthreads();
  if (tid < 2) {
    const int qq = R0 / HW_DIM + tid;
    if (qq < QN) atomicAdd(out + qq * WAYS + way, qsum[tid]);
  }
}

// ---------------------------------------------------------------------------
extern "C" void kernel_launch(void* const* d_in, const int* in_sizes, int n_in,
                              void* d_out, int out_size, void* d_ws, size_t ws_size,
                              hipStream_t stream) {
  const float* x1 = (const float*)d_in[0];
  const float* x2 = (const float*)d_in[1];
  float* out = (float*)d_out;
  u16* Abf = (u16*)d_ws;                                        // MPAD x 640 bf16
  u16* Sbf = (u16*)((char*)d_ws + (size_t)MPAD * C_DIM * 2);    // 5 x NPAD x 640

  hipLaunchKernelGGL(zero_pad, dim3(1432), dim3(256), 0, stream, Abf, Sbf, out);
  hipLaunchKernelGGL(prep_norm_transpose, dim3(QN * 7), dim3(256), 0, stream,
                     x1, Abf, 0);
  hipLaunchKernelGGL(prep_norm_transpose, dim3(SN * 7), dim3(256), 0, stream,
                     x2, Sbf, 1);
  hipLaunchKernelGGL(simtopk, dim3(WAYS * MBLK), dim3(256), 0, stream,
                     Abf, Sbf, out);
}